// Round 7
// baseline (330.988 us; speedup 1.0000x reference)
//
#include <hip/hip_runtime.h>
#include <math.h>

// Problem constants
#define BN_ 512     // B*NVARS
#define T_  128
#define C_  128
#define H_  8
#define D_  16
#define F_  256
#define M_  65536   // BN_*T_

typedef __bf16 bf16x8 __attribute__((ext_vector_type(8)));
typedef float f32x4 __attribute__((ext_vector_type(4)));
union U8 { uint2 d[2]; bf16x8 v; unsigned short u[8]; };

__device__ inline unsigned short f2bf(float x) {
  union { float f; unsigned int u; } a; a.f = x;
  unsigned int r = a.u + 0x7fffu + ((a.u >> 16) & 1u);
  return (unsigned short)(r >> 16);
}
__device__ inline float bf2f(unsigned short h) {
  return __uint_as_float((unsigned int)h << 16);
}
// exact-enough GELU: erf via A&S 7.1.26, |eps|<=1.5e-7
__device__ inline float gelu_f(float x) {
  float z  = x * 0.70710678118654752f;
  float az = fabsf(z);
  float t  = 1.0f / (1.0f + 0.3275911f * az);
  float poly = ((((1.061405429f*t - 1.453152027f)*t + 1.421413741f)*t
                 - 0.284496736f)*t + 0.254829592f)*t;
  float e  = __expf(-z*z);
  float er = 1.0f - poly*e;
  er = (z < 0.0f) ? -er : er;
  return 0.5f * x * (1.0f + er);
}

// ---------------------------------------------------------------------------
// K1: qkv = src @ qkv_w + qkv_b, split-bf16 MFMA (3-term), M=32 rows/block.
// ---------------------------------------------------------------------------
__global__ __launch_bounds__(256, 4) void k_qkv(
    const float* __restrict__ src, const unsigned short* __restrict__ wqh,
    const unsigned short* __restrict__ wql, const float* __restrict__ bias,
    float* __restrict__ qb, float* __restrict__ kb, float* __restrict__ vb) {
  __shared__ __align__(16) unsigned short Ah[8*512], Al[8*512];
  const int tid = threadIdx.x;
  const int lane = tid & 63, w = tid >> 6;
  const int cl = lane & 15, g = lane >> 4;
  const size_t rb = (size_t)blockIdx.x * 32;

  #pragma unroll
  for (int it=0; it<4; ++it) {
    int idx = it*256 + tid;
    int r = idx >> 5, c4 = (idx & 31)*4;
    float4 v = *(const float4*)&src[(rb + r)*128 + c4];
    float vv[4] = {v.x, v.y, v.z, v.w};
    int s = c4 >> 5, kl = c4 & 31;
    int g2 = (kl >> 2) & 3, j0 = (kl >> 4) << 2;
    int fi = ((r>>4)*4 + s)*512 + (g2*16 + (r & 15))*8 + j0;
    unsigned short h4[4], l4[4];
    #pragma unroll
    for (int e=0;e<4;++e) {
      h4[e] = f2bf(vv[e]);
      l4[e] = f2bf(vv[e] - bf2f(h4[e]));
    }
    *(uint2*)&Ah[fi] = make_uint2((unsigned)h4[0] | ((unsigned)h4[1]<<16),
                                  (unsigned)h4[2] | ((unsigned)h4[3]<<16));
    *(uint2*)&Al[fi] = make_uint2((unsigned)l4[0] | ((unsigned)l4[1]<<16),
                                  (unsigned)l4[2] | ((unsigned)l4[3]<<16));
  }
  __syncthreads();

  f32x4 acc[2][6];
  #pragma unroll
  for (int m=0;m<2;++m)
    #pragma unroll
    for (int n=0;n<6;++n) acc[m][n] = 0;

  #pragma unroll
  for (int s=0; s<4; ++s) {
    bf16x8 ah[2], al[2];
    #pragma unroll
    for (int m=0;m<2;++m) {
      ah[m] = *(const bf16x8*)&Ah[(m*4+s)*512 + lane*8];
      al[m] = *(const bf16x8*)&Al[(m*4+s)*512 + lane*8];
    }
    #pragma unroll
    for (int nt=0; nt<6; ++nt) {
      int n = w*96 + nt*16 + cl;
      size_t fi = (size_t)((s*384 + n)*4 + g)*8;
      bf16x8 bh = *(const bf16x8*)(wqh + fi);
      bf16x8 bl = *(const bf16x8*)(wql + fi);
      #pragma unroll
      for (int m=0;m<2;++m) {
        acc[m][nt] = __builtin_amdgcn_mfma_f32_16x16x32_bf16(ah[m], bh, acc[m][nt], 0,0,0);
        acc[m][nt] = __builtin_amdgcn_mfma_f32_16x16x32_bf16(ah[m], bl, acc[m][nt], 0,0,0);
        acc[m][nt] = __builtin_amdgcn_mfma_f32_16x16x32_bf16(al[m], bh, acc[m][nt], 0,0,0);
      }
    }
  }

  #pragma unroll
  for (int nt=0; nt<6; ++nt) {
    int n = w*96 + nt*16 + cl;
    int which = n >> 7, loc = n & 127;
    int h = loc >> 4, d = loc & 15;
    float* outb = (which==0) ? qb : ((which==1) ? kb : vb);
    float bv = bias[n];
    #pragma unroll
    for (int m=0;m<2;++m) {
      #pragma unroll
      for (int r=0;r<4;++r) {
        size_t row = rb + m*16 + g*4 + r;
        int bn = (int)(row >> 7), t = (int)(row & 127);
        outb[(((size_t)(bn*8 + h))*128 + t)*16 + d] = acc[m][nt][r] + bv;
      }
    }
  }
}

// ---------------------------------------------------------------------------
// K2: per-(bn,h) attention, MFMA version. Writes o1/o2 as bf16 and fused
// per-channel partial sums (p12[block*128 + slot]).
// part layout: [br*64 + grp*32 + {0:sum,16:sq} + cl], br=o1/o2, grp=(e&1)
// ---------------------------------------------------------------------------
__global__ __launch_bounds__(256, 4) void k_attn(
    const float* __restrict__ qb, const float* __restrict__ kb,
    const float* __restrict__ vb, const unsigned short* __restrict__ ef,
    unsigned short* __restrict__ o1b, unsigned short* __restrict__ o2b,
    float* __restrict__ p12) {
  __shared__ __align__(16) unsigned short QFh[2048], QFl[2048];
  __shared__ __align__(16) unsigned short KFh[2048], KFl[2048];
  __shared__ __align__(16) unsigned short VF[2048];
  __shared__ __align__(16) unsigned short Vn[128*20];
  __shared__ __align__(16) unsigned short eqL[128*20], ekL[128*20];
  __shared__ __align__(16) float s2L[16*17];
  __shared__ float part[128];
  const int tid = threadIdx.x;
  const int lane = tid & 63, w = tid >> 6;
  const int cl = lane & 15, g = lane >> 4;
  const int bn = blockIdx.x >> 3, h = blockIdx.x & 7;
  const int h1 = h >> 1, hb = h & 1;
  const size_t base = (size_t)(bn*8 + h) * 2048;

  if (tid < 128) part[tid] = 0.f;

  {
    const int t = tid >> 1, d0 = (tid & 1) * 8;
    const int s = t >> 5, kk = t & 31;
    const int g2 = (kk >> 2) & 3;
    const int j = ((kk >> 4) << 2) | (kk & 3);
    const float* qp = &qb[base + t*16 + d0];
    const float* kp = &kb[base + t*16 + d0];
    const float* vp = &vb[base + t*16 + d0];
    float4 qa = *(const float4*)qp, qc = *(const float4*)(qp+4);
    float4 ka = *(const float4*)kp, kc = *(const float4*)(kp+4);
    float4 va = *(const float4*)vp, vc = *(const float4*)(vp+4);
    float qv[8] = {qa.x,qa.y,qa.z,qa.w,qc.x,qc.y,qc.z,qc.w};
    float kv[8] = {ka.x,ka.y,ka.z,ka.w,kc.x,kc.y,kc.z,kc.w};
    float vv[8] = {va.x,va.y,va.z,va.w,vc.x,vc.y,vc.z,vc.w};
    unsigned short vh[8];
    #pragma unroll
    for (int e2=0;e2<8;++e2) {
      int fi = s*512 + (g2*16 + d0 + e2)*8 + j;
      unsigned short qh = f2bf(qv[e2]);
      QFh[fi] = qh; QFl[fi] = f2bf(qv[e2] - bf2f(qh));
      unsigned short kh = f2bf(kv[e2]);
      KFh[fi] = kh; KFl[fi] = f2bf(kv[e2] - bf2f(kh));
      vh[e2] = f2bf(vv[e2]);
      VF[fi] = vh[e2];
    }
    unsigned int p0 = (unsigned)vh[0] | ((unsigned)vh[1]<<16);
    unsigned int p1 = (unsigned)vh[2] | ((unsigned)vh[3]<<16);
    unsigned int p2 = (unsigned)vh[4] | ((unsigned)vh[5]<<16);
    unsigned int p3 = (unsigned)vh[6] | ((unsigned)vh[7]<<16);
    *(uint2*)&Vn[t*20 + d0]     = make_uint2(p0,p1);
    *(uint2*)&Vn[t*20 + d0 + 4] = make_uint2(p2,p3);
  }
  __syncthreads();

  {
    f32x4 aq[2], ak[2];
    #pragma unroll
    for (int m=0;m<2;++m){ aq[m]=0; ak[m]=0; }
    #pragma unroll
    for (int s=0;s<4;++s) {
      bf16x8 qf = *(const bf16x8*)&QFh[s*512 + lane*8];
      bf16x8 kf = *(const bf16x8*)&KFh[s*512 + lane*8];
      #pragma unroll
      for (int m=0;m<2;++m) {
        int mt = w*2 + m;
        bf16x8 eA = *(const bf16x8*)&ef[(size_t)((mt*4 + s)*64 + lane)*8];
        aq[m] = __builtin_amdgcn_mfma_f32_16x16x32_bf16(eA, qf, aq[m], 0,0,0);
        ak[m] = __builtin_amdgcn_mfma_f32_16x16x32_bf16(eA, kf, ak[m], 0,0,0);
      }
    }
    #pragma unroll
    for (int m=0;m<2;++m)
      #pragma unroll
      for (int r=0;r<4;++r) {
        int row = w*32 + m*16 + g*4 + r;
        eqL[row*20 + cl] = f2bf(aq[m][r]);
        ekL[row*20 + cl] = f2bf(ak[m][r]);
      }
  }
  if (w == 3) {
    f32x4 a2; a2 = 0;
    #pragma unroll
    for (int s=0;s<4;++s) {
      bf16x8 qh = *(const bf16x8*)&QFh[s*512 + lane*8];
      bf16x8 ql = *(const bf16x8*)&QFl[s*512 + lane*8];
      bf16x8 kh = *(const bf16x8*)&KFh[s*512 + lane*8];
      bf16x8 kl = *(const bf16x8*)&KFl[s*512 + lane*8];
      a2 = __builtin_amdgcn_mfma_f32_16x16x32_bf16(qh, kh, a2, 0,0,0);
      a2 = __builtin_amdgcn_mfma_f32_16x16x32_bf16(qh, kl, a2, 0,0,0);
      a2 = __builtin_amdgcn_mfma_f32_16x16x32_bf16(ql, kh, a2, 0,0,0);
    }
    #pragma unroll
    for (int r=0;r<4;++r) {
      float sv = a2[r] * 11.313708498984761f;
      float mx = sv;
      mx = fmaxf(mx, __shfl_xor(mx, 1));
      mx = fmaxf(mx, __shfl_xor(mx, 2));
      mx = fmaxf(mx, __shfl_xor(mx, 4));
      mx = fmaxf(mx, __shfl_xor(mx, 8));
      float p = __expf(sv - mx);
      float sum = p;
      sum += __shfl_xor(sum, 1);
      sum += __shfl_xor(sum, 2);
      sum += __shfl_xor(sum, 4);
      sum += __shfl_xor(sum, 8);
      s2L[(g*4 + r)*17 + cl] = p / sum;
    }
  }
  __syncthreads();

  {
    f32x4 accS[8][2];
    #pragma unroll
    for (int kt=0;kt<8;++kt)
      #pragma unroll
      for (int qt=0;qt<2;++qt) accS[kt][qt] = 0;
    U8 eb[2];
    #pragma unroll
    for (int qt=0;qt<2;++qt) {
      eb[qt].d[0] = *(const uint2*)&eqL[(w*32 + qt*16 + cl)*20 + 4*g];
      eb[qt].d[1] = make_uint2(0,0);
    }
    #pragma unroll
    for (int kt=0;kt<8;++kt) {
      U8 ea;
      ea.d[0] = *(const uint2*)&ekL[(kt*16 + cl)*20 + 4*g];
      ea.d[1] = make_uint2(0,0);
      #pragma unroll
      for (int qt=0;qt<2;++qt)
        accS[kt][qt] = __builtin_amdgcn_mfma_f32_16x16x32_bf16(ea.v, eb[qt].v, accS[kt][qt], 0,0,0);
    }
    bf16x8 vfr[4];
    #pragma unroll
    for (int s=0;s<4;++s) vfr[s] = *(const bf16x8*)&VF[s*512 + lane*8];
    #pragma unroll
    for (int qt=0;qt<2;++qt) {
      float mx = -1e30f;
      #pragma unroll
      for (int kt=0;kt<8;++kt)
        #pragma unroll
        for (int r=0;r<4;++r) {
          accS[kt][qt][r] *= 4.0f;
          mx = fmaxf(mx, accS[kt][qt][r]);
        }
      mx = fmaxf(mx, __shfl_xor(mx, 16));
      mx = fmaxf(mx, __shfl_xor(mx, 32));
      float sum = 0.f;
      #pragma unroll
      for (int kt=0;kt<8;++kt)
        #pragma unroll
        for (int r=0;r<4;++r) {
          float p = __expf(accS[kt][qt][r] - mx);
          accS[kt][qt][r] = p; sum += p;
        }
      sum += __shfl_xor(sum, 16);
      sum += __shfl_xor(sum, 32);
      float inv = 1.0f / sum;
      f32x4 o; o = 0;
      #pragma unroll
      for (int s=0;s<4;++s) {
        U8 pa;
        #pragma unroll
        for (int j=0;j<8;++j)
          pa.u[j] = f2bf(accS[2*s + (j>>2)][qt][j&3] * inv);
        o = __builtin_amdgcn_mfma_f32_16x16x32_bf16(pa.v, vfr[s], o, 0,0,0);
      }
      #pragma unroll
      for (int r=0;r<4;++r) {
        int e = w*32 + qt*16 + g*4 + r;
        int t2 = hb*64 + (e>>1), cb = (e&1)*64 + h1*16 + cl;
        o1b[((size_t)(bn*128 + t2))*128 + cb] = f2bf(o[r]);
      }
      // fused bn1 partials (grp = r&1)
      float s0 = o[0]+o[2], q0 = o[0]*o[0]+o[2]*o[2];
      float s1 = o[1]+o[3], q1 = o[1]*o[1]+o[3]*o[3];
      s0 += __shfl_xor(s0,16); s0 += __shfl_xor(s0,32);
      q0 += __shfl_xor(q0,16); q0 += __shfl_xor(q0,32);
      s1 += __shfl_xor(s1,16); s1 += __shfl_xor(s1,32);
      q1 += __shfl_xor(q1,16); q1 += __shfl_xor(q1,32);
      if (g == 0) {
        atomicAdd(&part[cl],      s0);
        atomicAdd(&part[16+cl],   q0);
        atomicAdd(&part[32+cl],   s1);
        atomicAdd(&part[48+cl],   q1);
      }
    }
  }

  {
    U8 bb;
    #pragma unroll
    for (int j=0;j<4;++j) bb.u[j] = f2bf(s2L[cl*17 + 4*g + j]);
    bb.d[1] = make_uint2(0,0);
    #pragma unroll
    for (int m=0;m<2;++m) {
      int tt = w*2 + m;
      U8 va;
      va.d[0] = *(const uint2*)&Vn[(tt*16 + cl)*20 + 4*g];
      va.d[1] = make_uint2(0,0);
      f32x4 o; o = 0;
      o = __builtin_amdgcn_mfma_f32_16x16x32_bf16(va.v, bb.v, o, 0,0,0);
      #pragma unroll
      for (int r=0;r<4;++r) {
        int t = tt*16 + g*4 + r;
        int t2 = hb*64 + (t>>1), cb = (t&1)*64 + h1*16 + cl;
        o2b[((size_t)(bn*128 + t2))*128 + cb] = f2bf(o[r]);
      }
      float s0 = o[0]+o[2], q0 = o[0]*o[0]+o[2]*o[2];
      float s1 = o[1]+o[3], q1 = o[1]*o[1]+o[3]*o[3];
      s0 += __shfl_xor(s0,16); s0 += __shfl_xor(s0,32);
      q0 += __shfl_xor(q0,16); q0 += __shfl_xor(q0,32);
      s1 += __shfl_xor(s1,16); s1 += __shfl_xor(s1,32);
      q1 += __shfl_xor(q1,16); q1 += __shfl_xor(q1,32);
      if (g == 0) {
        atomicAdd(&part[64+cl],    s0);
        atomicAdd(&part[64+16+cl], q0);
        atomicAdd(&part[64+32+cl], s1);
        atomicAdd(&part[64+48+cl], q1);
      }
    }
  }
  __syncthreads();
  if (tid < 128) p12[(size_t)blockIdx.x*128 + tid] = part[tid];
}

// K4: finalize bn1/bn2 from fused partials -> scale/shift
// p12[block=(bn*8+h)][128]; channel c covered by h = 2*((c&63)>>4) + hb
__global__ __launch_bounds__(512) void k_fin12(
    const float* __restrict__ p12,
    const float* __restrict__ g1, const float* __restrict__ b1,
    const float* __restrict__ g2, const float* __restrict__ b2,
    float* __restrict__ stats) {
  __shared__ float rs[2][512];
  const int tid = threadIdx.x;
  const int half = tid >> 8;
  const int pair = tid & 255;
  const int br = pair >> 7, c = pair & 127;
  const int grp = c >> 6, h1 = (c & 63) >> 4, cl = c & 15;
  const int slot = br*64 + grp*32 + cl;
  float s = 0.f, q = 0.f;
  for (int bn = half*256; bn < half*256 + 256; ++bn) {
    const float* p = &p12[(size_t)(bn*8 + h1*2)*128];
    s += p[slot]      + p[128 + slot];
    q += p[slot + 16] + p[128 + slot + 16];
  }
  rs[0][tid] = s; rs[1][tid] = q;
  __syncthreads();
  if (tid < 256) {
    float ss = rs[0][tid] + rs[0][tid+256];
    float qq = rs[1][tid] + rs[1][tid+256];
    const float inv = 1.0f/65536.0f;
    float m = ss*inv, v = qq*inv - m*m;
    float r = rsqrtf(v + 1e-5f);
    int br2 = tid >> 7, c2 = tid & 127;
    float gv = br2 ? g2[c2] : g1[c2];
    float bv = br2 ? b2[c2] : b1[c2];
    float sc = r * gv;
    stats[br2*256 + c2]       = sc;
    stats[br2*256 + 128 + c2] = bv - m*sc;
  }
}

// ---------------------------------------------------------------------------
// K-prep: FFN weight frags (blocks 0..63), E frags (64..71),
//         qkv_w split hi/lo frags (72..95)
// ---------------------------------------------------------------------------
__global__ __launch_bounds__(256) void k_prep(
    const float* __restrict__ w11, const float* __restrict__ w12,
    const float* __restrict__ w21, const float* __restrict__ w22,
    const float* __restrict__ ema, const float* __restrict__ qkvw,
    unsigned short* __restrict__ wf, unsigned short* __restrict__ ef,
    unsigned short* __restrict__ wqh, unsigned short* __restrict__ wql) {
  if (blockIdx.x >= 72) {
    int tid3 = (blockIdx.x - 72)*256 + threadIdx.x;   // 0..6143
    int s = tid3 / 1536;
    int rem = tid3 - s*1536;
    int n = rem >> 2, g = rem & 3;
    size_t fi = (size_t)((s*384 + n)*4 + g)*8;
    #pragma unroll
    for (int j=0;j<8;++j) {
      int k = 32*s + 16*(j>>2) + 4*g + (j&3);
      float v = qkvw[(size_t)k*384 + n];
      unsigned short h = f2bf(v);
      wqh[fi+j] = h;
      wql[fi+j] = f2bf(v - bf2f(h));
    }
    return;
  }
  if (blockIdx.x >= 64) {
    int tid2 = (blockIdx.x - 64)*256 + threadIdx.x;   // 0..2047
    int mt = tid2 >> 8, s = (tid2 >> 6) & 3, lane = tid2 & 63;
    int cl = lane & 15, g = lane >> 4;
    unsigned short* dst = ef + (size_t)tid2*8;
    #pragma unroll
    for (int j=0;j<8;++j) {
      int k = 32*s + 16*(j>>2) + 4*g + (j&3);
      dst[j] = f2bf(ema[(size_t)(mt*16 + cl)*128 + k]);
    }
    return;
  }
  int tid = blockIdx.x*256 + threadIdx.x;   // 16384 total
  int m = tid >> 12;
  int idx = tid & 4095;
  const float* w; int N;
  if (m==0)      { w = w11; N = 256; }
  else if (m==1) { w = w12; N = 128; }
  else if (m==2) { w = w21; N = 256; }
  else           { w = w22; N = 128; }
  int g  = idx & 3;
  int sn = idx >> 2;
  int n  = (N==256) ? (sn & 255) : (sn & 127);
  int s  = (N==256) ? (sn >> 8)  : (sn >> 7);
  unsigned short* dst = wf + m*32768 + idx*8;
  #pragma unroll
  for (int j=0; j<8; ++j) {
    int k = s*32 + g*4 + (j&3) + 16*(j>>2);
    dst[j] = f2bf(w[(size_t)k*N + n]);
  }
}

// ---------------------------------------------------------------------------
// K5: fused dual FFN, bf16 MFMA. 512 thr / 8 waves; 16-col stripe per wave.
// o1/o2 inputs are bf16.
// ---------------------------------------------------------------------------
__global__ void k_ff(
    const unsigned short* __restrict__ o1b, const unsigned short* __restrict__ o2b,
    const float* __restrict__ src,
    const float* __restrict__ bb11, const float* __restrict__ bb12,
    const float* __restrict__ bb21, const float* __restrict__ bb22,
    const unsigned short* __restrict__ wf,
    const float* __restrict__ stats, float* __restrict__ outp,
    float* __restrict__ p3) {
  __shared__ __align__(16) unsigned short Xbf[64*128];  // 16 KB
  __shared__ __align__(16) unsigned short Hbf[64*128];  // 16 KB
  const int tid = threadIdx.x;
  const int lane = tid & 63, w = tid >> 6;          // w = 0..7
  const int cl = lane & 15, g = lane >> 4;
  const size_t rb = (size_t)blockIdx.x * 64;

  f32x4 acc2[4];
  #pragma unroll
  for (int m=0;m<4;++m) acc2[m] = 0;

  for (int br=0; br<2; ++br) {
    const unsigned short* xin = br ? o2b : o1b;
    const float* sc_ = stats + br*256;
    const float* sh_ = sc_ + 128;
    const unsigned short* w1f = wf + br*65536;
    const unsigned short* w2f = w1f + 32768;
    const float* b1g = br ? bb21 : bb11;

    __syncthreads();
    // stage X: bf16 load, bn, swizzled store (512 thr, 4 iters)
    #pragma unroll
    for (int it=0; it<4; ++it) {
      int idx = it*512 + tid;
      int row = idx >> 5, c4 = (idx & 31)*4;
      uint2 u = *(const uint2*)&xin[(rb+row)*128 + c4];
      float x0 = bf2f((unsigned short)(u.x & 0xffff));
      float x1 = bf2f((unsigned short)(u.x >> 16));
      float x2 = bf2f((unsigned short)(u.y & 0xffff));
      float x3 = bf2f((unsigned short)(u.y >> 16));
      unsigned int lo = f2bf(fmaf(x0, sc_[c4+0], sh_[c4+0]))
                      | ((unsigned int)f2bf(fmaf(x1, sc_[c4+1], sh_[c4+1])) << 16);
      unsigned int hi = f2bf(fmaf(x2, sc_[c4+2], sh_[c4+2]))
                      | ((unsigned int)f2bf(fmaf(x3, sc_[c4+3], sh_[c4+3])) << 16);
      unsigned int byteo = (unsigned)((row*256 + c4*2) ^ ((row&7)<<4));
      *(uint2*)((char*)Xbf + byteo) = make_uint2(lo, hi);
    }
    __syncthreads();

    #pragma unroll
    for (int hc=0; hc<2; ++hc) {
      f32x4 acc1[4];
      #pragma unroll
      for (int m=0;m<4;++m) acc1[m] = 0;

      bf16x8 bfs[4];
      #pragma unroll
      for (int s=0; s<4; ++s) {
        int n = hc*128 + w*16 + cl;
        bfs[s] = *(const bf16x8*)(w1f + (size_t)((s*256 + n)*4 + g)*8);
      }
      #pragma unroll
      for (int s=0; s<4; ++s) {
        #pragma unroll
        for (int m=0; m<4; ++m) {
          int row = m*16 + cl;
          U8 u;
          u.d[0] = *(uint2*)((char*)Xbf + (unsigned)((row*256 + (s*32 + g*4)*2)    ^ ((row&7)<<4)));
          u.d[1] = *(uint2*)((char*)Xbf + (unsigned)((row*256 + (s*32 +16+ g*4)*2) ^ ((row&7)<<4)));
          acc1[m] = __builtin_amdgcn_mfma_f32_16x16x32_bf16(u.v, bfs[s], acc1[m], 0, 0, 0);
        }
      }

      {
        int col = w*16 + cl;
        float bias = b1g[hc*128 + col];
        #pragma unroll
        for (int m=0; m<4; ++m) {
          #pragma unroll
          for (int r=0; r<4; ++r) {
            float y = gelu_f(acc1[m][r] + bias);
            int row = m*16 + g*4 + r;
            unsigned int byteo = (unsigned)((row*256 + col*2) ^ ((row&7)<<4));
            *(unsigned short*)((char*)Hbf + byteo) = f2bf(y);
          }
        }
      }
      __syncthreads();

      bf16x8 bf2[4];
      #pragma unroll
      for (int s2l=0; s2l<4; ++s2l) {
        int s2 = hc*4 + s2l;
        int n = w*16 + cl;
        bf2[s2l] = *(const bf16x8*)(w2f + (size_t)((s2*128 + n)*4 + g)*8);
      }
      #pragma unroll
      for (int s2l=0; s2l<4; ++s2l) {
        #pragma unroll
        for (int m=0; m<4; ++m) {
          int row = m*16 + cl;
          U8 u;
          u.d[0] = *(uint2*)((char*)Hbf + (unsigned)((row*256 + (s2l*32 + g*4)*2)    ^ ((row&7)<<4)));
          u.d[1] = *(uint2*)((char*)Hbf + (unsigned)((row*256 + (s2l*32 +16+ g*4)*2) ^ ((row&7)<<4)));
          acc2[m] = __builtin_amdgcn_mfma_f32_16x16x32_bf16(u.v, bf2[s2l], acc2[m], 0, 0, 0);
        }
      }
      __syncthreads();
    }
  }

  {
    int col = w*16 + cl;
    float bias = bb12[col] + bb22[col];
    float cs = 0.f, cq = 0.f;
    #pragma unroll
    for (int m=0; m<4; ++m) {
      #pragma unroll
      for (int r=0; r<4; ++r) {
        size_t row = rb + m*16 + g*4 + r;
        float o = src[row*128 + col] + acc2[m][r] + bias;
        outp[row*128 + col] = o;
        cs += o; cq = fmaf(o, o, cq);
      }
    }
    cs += __shfl_down(cs, 32); cs += __shfl_down(cs, 16);
    cq += __shfl_down(cq, 32); cq += __shfl_down(cq, 16);
    if (g == 0) {
      p3[(size_t)blockIdx.x*256 + col]       = cs;
      p3[(size_t)blockIdx.x*256 + 128 + col] = cq;
    }
  }
}

// K6: finalize bn3 -> scale3/shift3
__global__ __launch_bounds__(512) void k_fin3(
    const float* __restrict__ p3, const float* __restrict__ g3,
    const float* __restrict__ b3, float* __restrict__ stats) {
  __shared__ float rs[2][512];
  const int tid = threadIdx.x;
  const int c = tid & 127, part = tid >> 7;
  float s=0.f,q=0.f;
  for (int b=part; b<1024; b+=4) {
    s += p3[(size_t)b*256 + c];
    q += p3[(size_t)b*256 + 128 + c];
  }
  rs[0][tid]=s; rs[1][tid]=q;
  __syncthreads();
  if (tid < 128) {
    float a=0.f,bq=0.f;
    #pragma unroll
    for (int g=0; g<4; ++g){ a += rs[0][g*128+tid]; bq += rs[1][g*128+tid]; }
    const float inv = 1.0f/65536.0f;
    float m = a*inv, v = bq*inv - m*m;
    float r = rsqrtf(v + 1e-5f);
    float scv = r*g3[tid];
    stats[512 + tid] = scv;
    stats[640 + tid] = b3[tid] - m*scv;
  }
}

// K7: final batchnorm, in-place on d_out
__global__ __launch_bounds__(256) void k_bn3(
    float* __restrict__ outp, const float* __restrict__ stats) {
  const int i0 = blockIdx.x*256 + threadIdx.x;
  #pragma unroll
  for (int it=0; it<4; ++it) {
    size_t fi = ((size_t)i0 + (size_t)it*524288) * 4;
    int c = (int)(fi & 127);
    float4 v = *(float4*)&outp[fi];
    v.x = fmaf(v.x, stats[512+c+0], stats[640+c+0]);
    v.y = fmaf(v.y, stats[512+c+1], stats[640+c+1]);
    v.z = fmaf(v.z, stats[512+c+2], stats[640+c+2]);
    v.w = fmaf(v.w, stats[512+c+3], stats[640+c+3]);
    *(float4*)&outp[fi] = v;
  }
}

extern "C" void kernel_launch(void* const* d_in, const int* in_sizes, int n_in,
                              void* d_out, int out_size, void* d_ws, size_t ws_size,
                              hipStream_t stream) {
  const float* src   = (const float*)d_in[0];
  const float* qkv_w = (const float*)d_in[1];
  const float* qkv_b = (const float*)d_in[2];
  const float* ff1w1 = (const float*)d_in[3];
  const float* ff1b1 = (const float*)d_in[4];
  const float* ff1w2 = (const float*)d_in[5];
  const float* ff1b2 = (const float*)d_in[6];
  const float* ff2w1 = (const float*)d_in[7];
  const float* ff2b1 = (const float*)d_in[8];
  const float* ff2w2 = (const float*)d_in[9];
  const float* ff2b2 = (const float*)d_in[10];
  const float* g1 = (const float*)d_in[11];
  const float* b1 = (const float*)d_in[12];
  const float* g2 = (const float*)d_in[13];
  const float* b2 = (const float*)d_in[14];
  const float* g3 = (const float*)d_in[15];
  const float* b3 = (const float*)d_in[16];
  const float* ema = (const float*)d_in[17];

  float* ws = (float*)d_ws;
  float* qb  = ws;                    // 8388608 floats each
  float* kb  = qb + 8388608;
  float* vb  = kb + 8388608;
  unsigned short* o1b = (unsigned short*)(vb + 8388608);   // 8388608 bf16
  unsigned short* o2b = o1b + 8388608;
  float* p12 = (float*)(o2b + 8388608);  // 4096*128
  float* p3  = p12 + 524288;             // 1024*256
  float* stats = p3 + 262144;            // 768 (+pad)
  unsigned short* wfrag = (unsigned short*)(stats + 1024);  // 4*32768 bf16
  unsigned short* efrag = wfrag + 131072;                   // 16384 bf16
  unsigned short* wqh   = efrag + 16384;                    // 49152 bf16
  unsigned short* wql   = wqh + 49152;                      // 49152 bf16
  float* outp = (float*)d_out;

  k_prep<<<dim3(96), dim3(256), 0, stream>>>(ff1w1, ff1w2, ff2w1, ff2w2, ema,
                                             qkv_w, wfrag, efrag, wqh, wql);
  k_qkv<<<dim3(2048), dim3(256), 0, stream>>>(src, wqh, wql, qkv_b, qb, kb, vb);
  k_attn<<<dim3(4096), dim3(256), 0, stream>>>(qb, kb, vb, efrag, o1b, o2b, p12);
  k_fin12<<<dim3(1), dim3(512), 0, stream>>>(p12, g1, b1, g2, b2, stats);
  k_ff<<<dim3(1024), dim3(512), 0, stream>>>(o1b, o2b, src,
      ff1b1, ff1b2, ff2b1, ff2b2, wfrag, stats, outp, p3);
  k_fin3<<<dim3(1), dim3(512), 0, stream>>>(p3, g3, b3, stats);
  k_bn3<<<dim3(2048), dim3(256), 0, stream>>>(outp, stats);
}

// Round 8
// 209.955 us; speedup vs baseline: 1.5765x; 1.5765x over previous
//
#include <hip/hip_runtime.h>
#include <math.h>

// Problem constants
#define BN_ 512     // B*NVARS
#define T_  128
#define C_  128
#define H_  8
#define D_  16
#define F_  256
#define M_  65536   // BN_*T_

typedef __bf16 bf16x8 __attribute__((ext_vector_type(8)));
typedef float f32x4 __attribute__((ext_vector_type(4)));
union U8 { uint2 d[2]; bf16x8 v; unsigned short u[8]; };

__device__ inline unsigned short f2bf(float x) {
  union { float f; unsigned int u; } a; a.f = x;
  unsigned int r = a.u + 0x7fffu + ((a.u >> 16) & 1u);
  return (unsigned short)(r >> 16);
}
__device__ inline float bf2f(unsigned short h) {
  return __uint_as_float((unsigned int)h << 16);
}
// exact-enough GELU: erf via A&S 7.1.26, |eps|<=1.5e-7
__device__ inline float gelu_f(float x) {
  float z  = x * 0.70710678118654752f;
  float az = fabsf(z);
  float t  = 1.0f / (1.0f + 0.3275911f * az);
  float poly = ((((1.061405429f*t - 1.453152027f)*t + 1.421413741f)*t
                 - 0.284496736f)*t + 0.254829592f)*t;
  float e  = __expf(-z*z);
  float er = 1.0f - poly*e;
  er = (z < 0.0f) ? -er : er;
  return 0.5f * x * (1.0f + er);
}

// ---------------------------------------------------------------------------
// K1: qkv = src @ qkv_w + qkv_b, split-bf16 MFMA (3-term), M=32 rows/block.
// ---------------------------------------------------------------------------
__global__ __launch_bounds__(256, 4) void k_qkv(
    const float* __restrict__ src, const unsigned short* __restrict__ wqh,
    const unsigned short* __restrict__ wql, const float* __restrict__ bias,
    float* __restrict__ qb, float* __restrict__ kb, float* __restrict__ vb) {
  __shared__ __align__(16) unsigned short Ah[8*512], Al[8*512];
  const int tid = threadIdx.x;
  const int lane = tid & 63, w = tid >> 6;
  const int cl = lane & 15, g = lane >> 4;
  const size_t rb = (size_t)blockIdx.x * 32;

  #pragma unroll
  for (int it=0; it<4; ++it) {
    int idx = it*256 + tid;
    int r = idx >> 5, c4 = (idx & 31)*4;
    float4 v = *(const float4*)&src[(rb + r)*128 + c4];
    float vv[4] = {v.x, v.y, v.z, v.w};
    int s = c4 >> 5, kl = c4 & 31;
    int g2 = (kl >> 2) & 3, j0 = (kl >> 4) << 2;
    int fi = ((r>>4)*4 + s)*512 + (g2*16 + (r & 15))*8 + j0;
    unsigned short h4[4], l4[4];
    #pragma unroll
    for (int e=0;e<4;++e) {
      h4[e] = f2bf(vv[e]);
      l4[e] = f2bf(vv[e] - bf2f(h4[e]));
    }
    *(uint2*)&Ah[fi] = make_uint2((unsigned)h4[0] | ((unsigned)h4[1]<<16),
                                  (unsigned)h4[2] | ((unsigned)h4[3]<<16));
    *(uint2*)&Al[fi] = make_uint2((unsigned)l4[0] | ((unsigned)l4[1]<<16),
                                  (unsigned)l4[2] | ((unsigned)l4[3]<<16));
  }
  __syncthreads();

  f32x4 acc[2][6];
  #pragma unroll
  for (int m=0;m<2;++m)
    #pragma unroll
    for (int n=0;n<6;++n) acc[m][n] = 0;

  #pragma unroll
  for (int s=0; s<4; ++s) {
    bf16x8 ah[2], al[2];
    #pragma unroll
    for (int m=0;m<2;++m) {
      ah[m] = *(const bf16x8*)&Ah[(m*4+s)*512 + lane*8];
      al[m] = *(const bf16x8*)&Al[(m*4+s)*512 + lane*8];
    }
    #pragma unroll
    for (int nt=0; nt<6; ++nt) {
      int n = w*96 + nt*16 + cl;
      size_t fi = (size_t)((s*384 + n)*4 + g)*8;
      bf16x8 bh = *(const bf16x8*)(wqh + fi);
      bf16x8 bl = *(const bf16x8*)(wql + fi);
      #pragma unroll
      for (int m=0;m<2;++m) {
        acc[m][nt] = __builtin_amdgcn_mfma_f32_16x16x32_bf16(ah[m], bh, acc[m][nt], 0,0,0);
        acc[m][nt] = __builtin_amdgcn_mfma_f32_16x16x32_bf16(ah[m], bl, acc[m][nt], 0,0,0);
        acc[m][nt] = __builtin_amdgcn_mfma_f32_16x16x32_bf16(al[m], bh, acc[m][nt], 0,0,0);
      }
    }
  }

  #pragma unroll
  for (int nt=0; nt<6; ++nt) {
    int n = w*96 + nt*16 + cl;
    int which = n >> 7, loc = n & 127;
    int h = loc >> 4, d = loc & 15;
    float* outb = (which==0) ? qb : ((which==1) ? kb : vb);
    float bv = bias[n];
    #pragma unroll
    for (int m=0;m<2;++m) {
      #pragma unroll
      for (int r=0;r<4;++r) {
        size_t row = rb + m*16 + g*4 + r;
        int bn = (int)(row >> 7), t = (int)(row & 127);
        outb[(((size_t)(bn*8 + h))*128 + t)*16 + d] = acc[m][nt][r] + bv;
      }
    }
  }
}

// ---------------------------------------------------------------------------
// K2: per-(bn,h) attention, MFMA version. Writes o1/o2 as bf16 and fused
// per-channel partial sums (p12[block*128 + slot]).
// part layout: [br*64 + grp*32 + {0:sum,16:sq} + cl], br=o1/o2, grp=(e&1)
// ---------------------------------------------------------------------------
__global__ __launch_bounds__(256, 4) void k_attn(
    const float* __restrict__ qb, const float* __restrict__ kb,
    const float* __restrict__ vb, const unsigned short* __restrict__ ef,
    unsigned short* __restrict__ o1b, unsigned short* __restrict__ o2b,
    float* __restrict__ p12) {
  __shared__ __align__(16) unsigned short QFh[2048], QFl[2048];
  __shared__ __align__(16) unsigned short KFh[2048], KFl[2048];
  __shared__ __align__(16) unsigned short VF[2048];
  __shared__ __align__(16) unsigned short Vn[128*20];
  __shared__ __align__(16) unsigned short eqL[128*20], ekL[128*20];
  __shared__ __align__(16) float s2L[16*17];
  __shared__ float part[128];
  const int tid = threadIdx.x;
  const int lane = tid & 63, w = tid >> 6;
  const int cl = lane & 15, g = lane >> 4;
  const int bn = blockIdx.x >> 3, h = blockIdx.x & 7;
  const int h1 = h >> 1, hb = h & 1;
  const size_t base = (size_t)(bn*8 + h) * 2048;

  if (tid < 128) part[tid] = 0.f;

  {
    const int t = tid >> 1, d0 = (tid & 1) * 8;
    const int s = t >> 5, kk = t & 31;
    const int g2 = (kk >> 2) & 3;
    const int j = ((kk >> 4) << 2) | (kk & 3);
    const float* qp = &qb[base + t*16 + d0];
    const float* kp = &kb[base + t*16 + d0];
    const float* vp = &vb[base + t*16 + d0];
    float4 qa = *(const float4*)qp, qc = *(const float4*)(qp+4);
    float4 ka = *(const float4*)kp, kc = *(const float4*)(kp+4);
    float4 va = *(const float4*)vp, vc = *(const float4*)(vp+4);
    float qv[8] = {qa.x,qa.y,qa.z,qa.w,qc.x,qc.y,qc.z,qc.w};
    float kv[8] = {ka.x,ka.y,ka.z,ka.w,kc.x,kc.y,kc.z,kc.w};
    float vv[8] = {va.x,va.y,va.z,va.w,vc.x,vc.y,vc.z,vc.w};
    unsigned short vh[8];
    #pragma unroll
    for (int e2=0;e2<8;++e2) {
      int fi = s*512 + (g2*16 + d0 + e2)*8 + j;
      unsigned short qh = f2bf(qv[e2]);
      QFh[fi] = qh; QFl[fi] = f2bf(qv[e2] - bf2f(qh));
      unsigned short kh = f2bf(kv[e2]);
      KFh[fi] = kh; KFl[fi] = f2bf(kv[e2] - bf2f(kh));
      vh[e2] = f2bf(vv[e2]);
      VF[fi] = vh[e2];
    }
    unsigned int p0 = (unsigned)vh[0] | ((unsigned)vh[1]<<16);
    unsigned int p1 = (unsigned)vh[2] | ((unsigned)vh[3]<<16);
    unsigned int p2 = (unsigned)vh[4] | ((unsigned)vh[5]<<16);
    unsigned int p3 = (unsigned)vh[6] | ((unsigned)vh[7]<<16);
    *(uint2*)&Vn[t*20 + d0]     = make_uint2(p0,p1);
    *(uint2*)&Vn[t*20 + d0 + 4] = make_uint2(p2,p3);
  }
  __syncthreads();

  {
    f32x4 aq[2], ak[2];
    #pragma unroll
    for (int m=0;m<2;++m){ aq[m]=0; ak[m]=0; }
    #pragma unroll
    for (int s=0;s<4;++s) {
      bf16x8 qf = *(const bf16x8*)&QFh[s*512 + lane*8];
      bf16x8 kf = *(const bf16x8*)&KFh[s*512 + lane*8];
      #pragma unroll
      for (int m=0;m<2;++m) {
        int mt = w*2 + m;
        bf16x8 eA = *(const bf16x8*)&ef[(size_t)((mt*4 + s)*64 + lane)*8];
        aq[m] = __builtin_amdgcn_mfma_f32_16x16x32_bf16(eA, qf, aq[m], 0,0,0);
        ak[m] = __builtin_amdgcn_mfma_f32_16x16x32_bf16(eA, kf, ak[m], 0,0,0);
      }
    }
    #pragma unroll
    for (int m=0;m<2;++m)
      #pragma unroll
      for (int r=0;r<4;++r) {
        int row = w*32 + m*16 + g*4 + r;
        eqL[row*20 + cl] = f2bf(aq[m][r]);
        ekL[row*20 + cl] = f2bf(ak[m][r]);
      }
  }
  if (w == 3) {
    f32x4 a2; a2 = 0;
    #pragma unroll
    for (int s=0;s<4;++s) {
      bf16x8 qh = *(const bf16x8*)&QFh[s*512 + lane*8];
      bf16x8 ql = *(const bf16x8*)&QFl[s*512 + lane*8];
      bf16x8 kh = *(const bf16x8*)&KFh[s*512 + lane*8];
      bf16x8 kl = *(const bf16x8*)&KFl[s*512 + lane*8];
      a2 = __builtin_amdgcn_mfma_f32_16x16x32_bf16(qh, kh, a2, 0,0,0);
      a2 = __builtin_amdgcn_mfma_f32_16x16x32_bf16(qh, kl, a2, 0,0,0);
      a2 = __builtin_amdgcn_mfma_f32_16x16x32_bf16(ql, kh, a2, 0,0,0);
    }
    #pragma unroll
    for (int r=0;r<4;++r) {
      float sv = a2[r] * 11.313708498984761f;
      float mx = sv;
      mx = fmaxf(mx, __shfl_xor(mx, 1));
      mx = fmaxf(mx, __shfl_xor(mx, 2));
      mx = fmaxf(mx, __shfl_xor(mx, 4));
      mx = fmaxf(mx, __shfl_xor(mx, 8));
      float p = __expf(sv - mx);
      float sum = p;
      sum += __shfl_xor(sum, 1);
      sum += __shfl_xor(sum, 2);
      sum += __shfl_xor(sum, 4);
      sum += __shfl_xor(sum, 8);
      s2L[(g*4 + r)*17 + cl] = p / sum;
    }
  }
  __syncthreads();

  {
    f32x4 accS[8][2];
    #pragma unroll
    for (int kt=0;kt<8;++kt)
      #pragma unroll
      for (int qt=0;qt<2;++qt) accS[kt][qt] = 0;
    U8 eb[2];
    #pragma unroll
    for (int qt=0;qt<2;++qt) {
      eb[qt].d[0] = *(const uint2*)&eqL[(w*32 + qt*16 + cl)*20 + 4*g];
      eb[qt].d[1] = make_uint2(0,0);
    }
    #pragma unroll
    for (int kt=0;kt<8;++kt) {
      U8 ea;
      ea.d[0] = *(const uint2*)&ekL[(kt*16 + cl)*20 + 4*g];
      ea.d[1] = make_uint2(0,0);
      #pragma unroll
      for (int qt=0;qt<2;++qt)
        accS[kt][qt] = __builtin_amdgcn_mfma_f32_16x16x32_bf16(ea.v, eb[qt].v, accS[kt][qt], 0,0,0);
    }
    bf16x8 vfr[4];
    #pragma unroll
    for (int s=0;s<4;++s) vfr[s] = *(const bf16x8*)&VF[s*512 + lane*8];
    #pragma unroll
    for (int qt=0;qt<2;++qt) {
      float mx = -1e30f;
      #pragma unroll
      for (int kt=0;kt<8;++kt)
        #pragma unroll
        for (int r=0;r<4;++r) {
          accS[kt][qt][r] *= 4.0f;
          mx = fmaxf(mx, accS[kt][qt][r]);
        }
      mx = fmaxf(mx, __shfl_xor(mx, 16));
      mx = fmaxf(mx, __shfl_xor(mx, 32));
      float sum = 0.f;
      #pragma unroll
      for (int kt=0;kt<8;++kt)
        #pragma unroll
        for (int r=0;r<4;++r) {
          float p = __expf(accS[kt][qt][r] - mx);
          accS[kt][qt][r] = p; sum += p;
        }
      sum += __shfl_xor(sum, 16);
      sum += __shfl_xor(sum, 32);
      float inv = 1.0f / sum;
      f32x4 o; o = 0;
      #pragma unroll
      for (int s=0;s<4;++s) {
        U8 pa;
        #pragma unroll
        for (int j=0;j<8;++j)
          pa.u[j] = f2bf(accS[2*s + (j>>2)][qt][j&3] * inv);
        o = __builtin_amdgcn_mfma_f32_16x16x32_bf16(pa.v, vfr[s], o, 0,0,0);
      }
      #pragma unroll
      for (int r=0;r<4;++r) {
        int e = w*32 + qt*16 + g*4 + r;
        int t2 = hb*64 + (e>>1), cb = (e&1)*64 + h1*16 + cl;
        o1b[((size_t)(bn*128 + t2))*128 + cb] = f2bf(o[r]);
      }
      // fused bn1 partials (grp = r&1)
      float s0 = o[0]+o[2], q0 = o[0]*o[0]+o[2]*o[2];
      float s1 = o[1]+o[3], q1 = o[1]*o[1]+o[3]*o[3];
      s0 += __shfl_xor(s0,16); s0 += __shfl_xor(s0,32);
      q0 += __shfl_xor(q0,16); q0 += __shfl_xor(q0,32);
      s1 += __shfl_xor(s1,16); s1 += __shfl_xor(s1,32);
      q1 += __shfl_xor(q1,16); q1 += __shfl_xor(q1,32);
      if (g == 0) {
        atomicAdd(&part[cl],      s0);
        atomicAdd(&part[16+cl],   q0);
        atomicAdd(&part[32+cl],   s1);
        atomicAdd(&part[48+cl],   q1);
      }
    }
  }

  {
    U8 bb;
    #pragma unroll
    for (int j=0;j<4;++j) bb.u[j] = f2bf(s2L[cl*17 + 4*g + j]);
    bb.d[1] = make_uint2(0,0);
    #pragma unroll
    for (int m=0;m<2;++m) {
      int tt = w*2 + m;
      U8 va;
      va.d[0] = *(const uint2*)&Vn[(tt*16 + cl)*20 + 4*g];
      va.d[1] = make_uint2(0,0);
      f32x4 o; o = 0;
      o = __builtin_amdgcn_mfma_f32_16x16x32_bf16(va.v, bb.v, o, 0,0,0);
      #pragma unroll
      for (int r=0;r<4;++r) {
        int t = tt*16 + g*4 + r;
        int t2 = hb*64 + (t>>1), cb = (t&1)*64 + h1*16 + cl;
        o2b[((size_t)(bn*128 + t2))*128 + cb] = f2bf(o[r]);
      }
      float s0 = o[0]+o[2], q0 = o[0]*o[0]+o[2]*o[2];
      float s1 = o[1]+o[3], q1 = o[1]*o[1]+o[3]*o[3];
      s0 += __shfl_xor(s0,16); s0 += __shfl_xor(s0,32);
      q0 += __shfl_xor(q0,16); q0 += __shfl_xor(q0,32);
      s1 += __shfl_xor(s1,16); s1 += __shfl_xor(s1,32);
      q1 += __shfl_xor(q1,16); q1 += __shfl_xor(q1,32);
      if (g == 0) {
        atomicAdd(&part[64+cl],    s0);
        atomicAdd(&part[64+16+cl], q0);
        atomicAdd(&part[64+32+cl], s1);
        atomicAdd(&part[64+48+cl], q1);
      }
    }
  }
  __syncthreads();
  if (tid < 128) p12[(size_t)blockIdx.x*128 + tid] = part[tid];
}

// ---------------------------------------------------------------------------
// K-red12: tree-reduce p12[4096][128] -> q12[128][128]
// row = chunk*8 + h; q12[row][slot] = sum over 32 bn of p12[(chunk*32+t)*8+h]
// ---------------------------------------------------------------------------
__global__ __launch_bounds__(256) void k_red12(
    const float* __restrict__ p12, float* __restrict__ q12) {
  __shared__ float red[256];
  const int tid = threadIdx.x;
  const int slot = tid & 127, half = tid >> 7;
  const int h = blockIdx.x & 7, chunk = blockIdx.x >> 3;
  float s = 0.f;
  for (int t = half; t < 32; t += 2)
    s += p12[(size_t)((chunk*32 + t)*8 + h)*128 + slot];
  red[tid] = s;
  __syncthreads();
  if (tid < 128)
    q12[(size_t)blockIdx.x*128 + tid] = red[tid] + red[tid + 128];
}

// K4: finalize bn1/bn2 from q12 (64KB, L2-resident)
__global__ __launch_bounds__(256) void k_fin12(
    const float* __restrict__ q12,
    const float* __restrict__ g1, const float* __restrict__ b1,
    const float* __restrict__ g2, const float* __restrict__ b2,
    float* __restrict__ stats) {
  const int tid = threadIdx.x;       // 0..255
  const int br = tid >> 7, c = tid & 127;
  const int grp = c >> 6, h1 = (c & 63) >> 4, cl = c & 15;
  const int slot = br*64 + grp*32 + cl;
  float s = 0.f, q = 0.f;
  #pragma unroll 4
  for (int chunk = 0; chunk < 16; ++chunk) {
    const float* p0 = &q12[(size_t)(chunk*8 + h1*2)*128];
    s += p0[slot]      + p0[128 + slot];
    q += p0[slot + 16] + p0[128 + slot + 16];
  }
  const float inv = 1.0f/65536.0f;
  float m = s*inv, v = q*inv - m*m;
  float r = rsqrtf(v + 1e-5f);
  float gv = br ? g2[c] : g1[c];
  float bv = br ? b2[c] : b1[c];
  float sc = r * gv;
  stats[br*256 + c]       = sc;
  stats[br*256 + 128 + c] = bv - m*sc;
}

// ---------------------------------------------------------------------------
// K-prep: FFN weight frags (blocks 0..63), E frags (64..71),
//         qkv_w split hi/lo frags (72..95)
// ---------------------------------------------------------------------------
__global__ __launch_bounds__(256) void k_prep(
    const float* __restrict__ w11, const float* __restrict__ w12,
    const float* __restrict__ w21, const float* __restrict__ w22,
    const float* __restrict__ ema, const float* __restrict__ qkvw,
    unsigned short* __restrict__ wf, unsigned short* __restrict__ ef,
    unsigned short* __restrict__ wqh, unsigned short* __restrict__ wql) {
  if (blockIdx.x >= 72) {
    int tid3 = (blockIdx.x - 72)*256 + threadIdx.x;   // 0..6143
    int s = tid3 / 1536;
    int rem = tid3 - s*1536;
    int n = rem >> 2, g = rem & 3;
    size_t fi = (size_t)((s*384 + n)*4 + g)*8;
    #pragma unroll
    for (int j=0;j<8;++j) {
      int k = 32*s + 16*(j>>2) + 4*g + (j&3);
      float v = qkvw[(size_t)k*384 + n];
      unsigned short h = f2bf(v);
      wqh[fi+j] = h;
      wql[fi+j] = f2bf(v - bf2f(h));
    }
    return;
  }
  if (blockIdx.x >= 64) {
    int tid2 = (blockIdx.x - 64)*256 + threadIdx.x;   // 0..2047
    int mt = tid2 >> 8, s = (tid2 >> 6) & 3, lane = tid2 & 63;
    int cl = lane & 15, g = lane >> 4;
    unsigned short* dst = ef + (size_t)tid2*8;
    #pragma unroll
    for (int j=0;j<8;++j) {
      int k = 32*s + 16*(j>>2) + 4*g + (j&3);
      dst[j] = f2bf(ema[(size_t)(mt*16 + cl)*128 + k]);
    }
    return;
  }
  int tid = blockIdx.x*256 + threadIdx.x;   // 16384 total
  int m = tid >> 12;
  int idx = tid & 4095;
  const float* w; int N;
  if (m==0)      { w = w11; N = 256; }
  else if (m==1) { w = w12; N = 128; }
  else if (m==2) { w = w21; N = 256; }
  else           { w = w22; N = 128; }
  int g  = idx & 3;
  int sn = idx >> 2;
  int n  = (N==256) ? (sn & 255) : (sn & 127);
  int s  = (N==256) ? (sn >> 8)  : (sn >> 7);
  unsigned short* dst = wf + m*32768 + idx*8;
  #pragma unroll
  for (int j=0; j<8; ++j) {
    int k = s*32 + g*4 + (j&3) + 16*(j>>2);
    dst[j] = f2bf(w[(size_t)k*N + n]);
  }
}

// ---------------------------------------------------------------------------
// K5: fused dual FFN, bf16 MFMA. 512 thr / 8 waves; 16-col stripe per wave.
// o1/o2 inputs are bf16.
// ---------------------------------------------------------------------------
__global__ void k_ff(
    const unsigned short* __restrict__ o1b, const unsigned short* __restrict__ o2b,
    const float* __restrict__ src,
    const float* __restrict__ bb11, const float* __restrict__ bb12,
    const float* __restrict__ bb21, const float* __restrict__ bb22,
    const unsigned short* __restrict__ wf,
    const float* __restrict__ stats, float* __restrict__ outp,
    float* __restrict__ p3) {
  __shared__ __align__(16) unsigned short Xbf[64*128];  // 16 KB
  __shared__ __align__(16) unsigned short Hbf[64*128];  // 16 KB
  const int tid = threadIdx.x;
  const int lane = tid & 63, w = tid >> 6;          // w = 0..7
  const int cl = lane & 15, g = lane >> 4;
  const size_t rb = (size_t)blockIdx.x * 64;

  f32x4 acc2[4];
  #pragma unroll
  for (int m=0;m<4;++m) acc2[m] = 0;

  for (int br=0; br<2; ++br) {
    const unsigned short* xin = br ? o2b : o1b;
    const float* sc_ = stats + br*256;
    const float* sh_ = sc_ + 128;
    const unsigned short* w1f = wf + br*65536;
    const unsigned short* w2f = w1f + 32768;
    const float* b1g = br ? bb21 : bb11;

    __syncthreads();
    // stage X: bf16 load, bn, swizzled store (512 thr, 4 iters)
    #pragma unroll
    for (int it=0; it<4; ++it) {
      int idx = it*512 + tid;
      int row = idx >> 5, c4 = (idx & 31)*4;
      uint2 u = *(const uint2*)&xin[(rb+row)*128 + c4];
      float x0 = bf2f((unsigned short)(u.x & 0xffff));
      float x1 = bf2f((unsigned short)(u.x >> 16));
      float x2 = bf2f((unsigned short)(u.y & 0xffff));
      float x3 = bf2f((unsigned short)(u.y >> 16));
      unsigned int lo = f2bf(fmaf(x0, sc_[c4+0], sh_[c4+0]))
                      | ((unsigned int)f2bf(fmaf(x1, sc_[c4+1], sh_[c4+1])) << 16);
      unsigned int hi = f2bf(fmaf(x2, sc_[c4+2], sh_[c4+2]))
                      | ((unsigned int)f2bf(fmaf(x3, sc_[c4+3], sh_[c4+3])) << 16);
      unsigned int byteo = (unsigned)((row*256 + c4*2) ^ ((row&7)<<4));
      *(uint2*)((char*)Xbf + byteo) = make_uint2(lo, hi);
    }
    __syncthreads();

    #pragma unroll
    for (int hc=0; hc<2; ++hc) {
      f32x4 acc1[4];
      #pragma unroll
      for (int m=0;m<4;++m) acc1[m] = 0;

      bf16x8 bfs[4];
      #pragma unroll
      for (int s=0; s<4; ++s) {
        int n = hc*128 + w*16 + cl;
        bfs[s] = *(const bf16x8*)(w1f + (size_t)((s*256 + n)*4 + g)*8);
      }
      #pragma unroll
      for (int s=0; s<4; ++s) {
        #pragma unroll
        for (int m=0; m<4; ++m) {
          int row = m*16 + cl;
          U8 u;
          u.d[0] = *(uint2*)((char*)Xbf + (unsigned)((row*256 + (s*32 + g*4)*2)    ^ ((row&7)<<4)));
          u.d[1] = *(uint2*)((char*)Xbf + (unsigned)((row*256 + (s*32 +16+ g*4)*2) ^ ((row&7)<<4)));
          acc1[m] = __builtin_amdgcn_mfma_f32_16x16x32_bf16(u.v, bfs[s], acc1[m], 0, 0, 0);
        }
      }

      {
        int col = w*16 + cl;
        float bias = b1g[hc*128 + col];
        #pragma unroll
        for (int m=0; m<4; ++m) {
          #pragma unroll
          for (int r=0; r<4; ++r) {
            float y = gelu_f(acc1[m][r] + bias);
            int row = m*16 + g*4 + r;
            unsigned int byteo = (unsigned)((row*256 + col*2) ^ ((row&7)<<4));
            *(unsigned short*)((char*)Hbf + byteo) = f2bf(y);
          }
        }
      }
      __syncthreads();

      bf16x8 bf2[4];
      #pragma unroll
      for (int s2l=0; s2l<4; ++s2l) {
        int s2 = hc*4 + s2l;
        int n = w*16 + cl;
        bf2[s2l] = *(const bf16x8*)(w2f + (size_t)((s2*128 + n)*4 + g)*8);
      }
      #pragma unroll
      for (int s2l=0; s2l<4; ++s2l) {
        #pragma unroll
        for (int m=0; m<4; ++m) {
          int row = m*16 + cl;
          U8 u;
          u.d[0] = *(uint2*)((char*)Hbf + (unsigned)((row*256 + (s2l*32 + g*4)*2)    ^ ((row&7)<<4)));
          u.d[1] = *(uint2*)((char*)Hbf + (unsigned)((row*256 + (s2l*32 +16+ g*4)*2) ^ ((row&7)<<4)));
          acc2[m] = __builtin_amdgcn_mfma_f32_16x16x32_bf16(u.v, bf2[s2l], acc2[m], 0, 0, 0);
        }
      }
      __syncthreads();
    }
  }

  {
    int col = w*16 + cl;
    float bias = bb12[col] + bb22[col];
    float cs = 0.f, cq = 0.f;
    #pragma unroll
    for (int m=0; m<4; ++m) {
      #pragma unroll
      for (int r=0; r<4; ++r) {
        size_t row = rb + m*16 + g*4 + r;
        float o = src[row*128 + col] + acc2[m][r] + bias;
        outp[row*128 + col] = o;
        cs += o; cq = fmaf(o, o, cq);
      }
    }
    cs += __shfl_down(cs, 32); cs += __shfl_down(cs, 16);
    cq += __shfl_down(cq, 32); cq += __shfl_down(cq, 16);
    if (g == 0) {
      p3[(size_t)blockIdx.x*256 + col]       = cs;
      p3[(size_t)blockIdx.x*256 + 128 + col] = cq;
    }
  }
}

// K-red3: tree-reduce p3[1024][256] -> q3[32][256]
__global__ __launch_bounds__(256) void k_red3(
    const float* __restrict__ p3, float* __restrict__ q3) {
  const int tid = threadIdx.x;
  float s = 0.f;
  const int b0 = blockIdx.x*32;
  for (int b = b0; b < b0 + 32; ++b)
    s += p3[(size_t)b*256 + tid];
  q3[(size_t)blockIdx.x*256 + tid] = s;
}

// K6: finalize bn3 from q3 (32KB)
__global__ __launch_bounds__(256) void k_fin3(
    const float* __restrict__ q3, const float* __restrict__ g3,
    const float* __restrict__ b3, float* __restrict__ stats) {
  __shared__ float acc[256];
  const int tid = threadIdx.x;
  float s = 0.f;
  #pragma unroll 4
  for (int i = 0; i < 32; ++i) s += q3[i*256 + tid];
  acc[tid] = s;
  __syncthreads();
  if (tid < 128) {
    const float inv = 1.0f/65536.0f;
    float m = acc[tid]*inv, v = acc[128+tid]*inv - m*m;
    float r = rsqrtf(v + 1e-5f);
    float scv = r*g3[tid];
    stats[512 + tid] = scv;
    stats[640 + tid] = b3[tid] - m*scv;
  }
}

// K7: final batchnorm, in-place on d_out
__global__ __launch_bounds__(256) void k_bn3(
    float* __restrict__ outp, const float* __restrict__ stats) {
  const int i0 = blockIdx.x*256 + threadIdx.x;
  #pragma unroll
  for (int it=0; it<4; ++it) {
    size_t fi = ((size_t)i0 + (size_t)it*524288) * 4;
    int c = (int)(fi & 127);
    float4 v = *(float4*)&outp[fi];
    v.x = fmaf(v.x, stats[512+c+0], stats[640+c+0]);
    v.y = fmaf(v.y, stats[512+c+1], stats[640+c+1]);
    v.z = fmaf(v.z, stats[512+c+2], stats[640+c+2]);
    v.w = fmaf(v.w, stats[512+c+3], stats[640+c+3]);
    *(float4*)&outp[fi] = v;
  }
}

extern "C" void kernel_launch(void* const* d_in, const int* in_sizes, int n_in,
                              void* d_out, int out_size, void* d_ws, size_t ws_size,
                              hipStream_t stream) {
  const float* src   = (const float*)d_in[0];
  const float* qkv_w = (const float*)d_in[1];
  const float* qkv_b = (const float*)d_in[2];
  const float* ff1w1 = (const float*)d_in[3];
  const float* ff1b1 = (const float*)d_in[4];
  const float* ff1w2 = (const float*)d_in[5];
  const float* ff1b2 = (const float*)d_in[6];
  const float* ff2w1 = (const float*)d_in[7];
  const float* ff2b1 = (const float*)d_in[8];
  const float* ff2w2 = (const float*)d_in[9];
  const float* ff2b2 = (const float*)d_in[10];
  const float* g1 = (const float*)d_in[11];
  const float* b1 = (const float*)d_in[12];
  const float* g2 = (const float*)d_in[13];
  const float* b2 = (const float*)d_in[14];
  const float* g3 = (const float*)d_in[15];
  const float* b3 = (const float*)d_in[16];
  const float* ema = (const float*)d_in[17];

  float* ws = (float*)d_ws;
  float* qb  = ws;                    // 8388608 floats each
  float* kb  = qb + 8388608;
  float* vb  = kb + 8388608;
  unsigned short* o1b = (unsigned short*)(vb + 8388608);   // 8388608 bf16
  unsigned short* o2b = o1b + 8388608;
  float* p12 = (float*)(o2b + 8388608);  // 4096*128
  float* p3  = p12 + 524288;             // 1024*256
  float* stats = p3 + 262144;            // 768 (+pad)
  unsigned short* wfrag = (unsigned short*)(stats + 1024);  // 4*32768 bf16
  unsigned short* efrag = wfrag + 131072;                   // 16384 bf16
  unsigned short* wqh   = efrag + 16384;                    // 49152 bf16
  unsigned short* wql   = wqh + 49152;                      // 49152 bf16
  float* q12 = (float*)(wql + 49152);    // 128*128
  float* q3  = q12 + 16384;              // 32*256
  float* outp = (float*)d_out;

  k_prep<<<dim3(96), dim3(256), 0, stream>>>(ff1w1, ff1w2, ff2w1, ff2w2, ema,
                                             qkv_w, wfrag, efrag, wqh, wql);
  k_qkv<<<dim3(2048), dim3(256), 0, stream>>>(src, wqh, wql, qkv_b, qb, kb, vb);
  k_attn<<<dim3(4096), dim3(256), 0, stream>>>(qb, kb, vb, efrag, o1b, o2b, p12);
  k_red12<<<dim3(128), dim3(256), 0, stream>>>(p12, q12);
  k_fin12<<<dim3(1), dim3(256), 0, stream>>>(q12, g1, b1, g2, b2, stats);
  k_ff<<<dim3(1024), dim3(512), 0, stream>>>(o1b, o2b, src,
      ff1b1, ff1b2, ff2b1, ff2b2, wfrag, stats, outp, p3);
  k_red3<<<dim3(32), dim3(256), 0, stream>>>(p3, q3);
  k_fin3<<<dim3(1), dim3(256), 0, stream>>>(q3, g3, b3, stats);
  k_bn3<<<dim3(2048), dim3(256), 0, stream>>>(outp, stats);
}